// Round 17
// baseline (111.929 us; speedup 1.0000x reference)
//
#include <hip/hip_runtime.h>
#include <stdint.h>
#include <math.h>

// Problem constants
#define BB   1024
#define TT   197
#define SS   196
#define DD   64
#define MM   200704   // BB*SS   (outputs per side)
#define GG   201728   // BB*TT   (param rows per table)
#define MROWS 256     // rows per MLP block (64 per wave)
#define MBLK  788     // GG/MROWS blocks per side
#define STRIP 28      // argmax strip rows (7 strips x 28 = 196)

using short8 = __attribute__((ext_vector_type(8))) short;   // 8 bf16 (A/B frag)
using f32x4  = __attribute__((ext_vector_type(4))) float;   // C/D frag

// ---------------- Threefry2x32 (exact JAX rolled variant) ----------------
static __host__ __device__ inline uint32_t rotl_(uint32_t x, int r) {
  return (x << r) | (x >> (32 - r));
}

static __host__ __device__ inline void tf2x32(uint32_t k0, uint32_t k1,
                                              uint32_t& x0, uint32_t& x1) {
  uint32_t ks2 = k0 ^ k1 ^ 0x1BD11BDAu;
  x0 += k0; x1 += k1;
  x0 += x1; x1 = rotl_(x1,13); x1 ^= x0;
  x0 += x1; x1 = rotl_(x1,15); x1 ^= x0;
  x0 += x1; x1 = rotl_(x1,26); x1 ^= x0;
  x0 += x1; x1 = rotl_(x1, 6); x1 ^= x0;
  x0 += k1;  x1 += ks2 + 1u;
  x0 += x1; x1 = rotl_(x1,17); x1 ^= x0;
  x0 += x1; x1 = rotl_(x1,29); x1 ^= x0;
  x0 += x1; x1 = rotl_(x1,16); x1 ^= x0;
  x0 += x1; x1 = rotl_(x1,24); x1 ^= x0;
  x0 += ks2; x1 += k0 + 2u;
  x0 += x1; x1 = rotl_(x1,13); x1 ^= x0;
  x0 += x1; x1 = rotl_(x1,15); x1 ^= x0;
  x0 += x1; x1 = rotl_(x1,26); x1 ^= x0;
  x0 += x1; x1 = rotl_(x1, 6); x1 ^= x0;
  x0 += k0;  x1 += k1 + 3u;
  x0 += x1; x1 = rotl_(x1,17); x1 ^= x0;
  x0 += x1; x1 = rotl_(x1,29); x1 ^= x0;
  x0 += x1; x1 = rotl_(x1,16); x1 ^= x0;
  x0 += x1; x1 = rotl_(x1,24); x1 ^= x0;
  x0 += k1;  x1 += ks2 + 4u;
  x0 += x1; x1 = rotl_(x1,13); x1 ^= x0;
  x0 += x1; x1 = rotl_(x1,15); x1 ^= x0;
  x0 += x1; x1 = rotl_(x1,26); x1 ^= x0;
  x0 += x1; x1 = rotl_(x1, 6); x1 ^= x0;
  x0 += ks2; x1 += k0 + 5u;
}

// XLA ErfInv (float32 Giles polynomial), exact non-contracted rounding.
static __device__ inline float erfinv_xla(float x) {
  float w = -log1pf(-__fmul_rn(x, x));
  float p;
  if (w < 5.0f) {
    w = __fsub_rn(w, 2.5f);
    p = 2.81022636e-08f;
    p = __fadd_rn(__fmul_rn(p, w), 3.43273939e-07f);
    p = __fadd_rn(__fmul_rn(p, w), -3.5233877e-06f);
    p = __fadd_rn(__fmul_rn(p, w), -4.39150654e-06f);
    p = __fadd_rn(__fmul_rn(p, w), 0.00021858087f);
    p = __fadd_rn(__fmul_rn(p, w), -0.00125372503f);
    p = __fadd_rn(__fmul_rn(p, w), -0.00417768164f);
    p = __fadd_rn(__fmul_rn(p, w), 0.246640727f);
    p = __fadd_rn(__fmul_rn(p, w), 1.50140941f);
  } else {
    w = __fsub_rn(sqrtf(w), 3.0f);
    p = -0.000200214257f;
    p = __fadd_rn(__fmul_rn(p, w), 0.000100950558f);
    p = __fadd_rn(__fmul_rn(p, w), 0.00134934322f);
    p = __fadd_rn(__fmul_rn(p, w), -0.00367342844f);
    p = __fadd_rn(__fmul_rn(p, w), 0.00573950773f);
    p = __fadd_rn(__fmul_rn(p, w), -0.0076224613f);
    p = __fadd_rn(__fmul_rn(p, w), 0.00943887047f);
    p = __fadd_rn(__fmul_rn(p, w), 1.00167406f);
    p = __fadd_rn(__fmul_rn(p, w), 2.83297682f);
  }
  return __fmul_rn(p, x);
}

// eps[e] of jax.random.normal under jax_threefry_partitionable=True:
// per-element counter PRF, counter (hi=0, lo=e), draw = x0out ^ x1out.
static __device__ inline float jax_normal_elem(uint32_t k0, uint32_t k1, uint32_t e) {
  uint32_t c0 = 0u, c1 = e;
  tf2x32(k0, k1, c0, c1);
  uint32_t bits = c0 ^ c1;
  float f = __fsub_rn(__uint_as_float((bits >> 9) | 0x3F800000u), 1.0f); // [0,1)
  const float lo = -0.99999994f;
  float u = fmaxf(lo, __fadd_rn(__fmul_rn(f, 2.0f), lo));
  return __fmul_rn(1.41421356237309515f, erfinv_xla(u));
}

static __device__ inline float softplus_(float x) {
  return __fadd_rn(fmaxf(x, 0.0f), log1pf(expf(-fabsf(x))));
}

static __device__ inline float sigmoid_(float x) {
  if (x >= 0.0f) return 1.0f / (1.0f + expf(-x));
  float e = expf(x);
  return e / (1.0f + e);
}

// 2-way truncation split of fp32 -> 2 bf16 terms (residual ~2^-17 relative)
static __device__ inline void split2w(float x, uint32_t& h1, uint32_t& h2) {
  uint32_t xb = __float_as_uint(x);
  h1 = xb & 0xFFFF0000u;
  float r1 = __fsub_rn(x, __uint_as_float(h1));   // exact
  h2 = __float_as_uint(r1) & 0xFFFF0000u;         // drops ~2^-17 residual
}

static __device__ inline void split8x2(f32x4 lo, f32x4 hi, short8& s1, short8& s2) {
  #pragma unroll
  for (int j = 0; j < 8; ++j) {
    float x = (j < 4) ? lo[j] : hi[j - 4];
    uint32_t h1, h2;
    split2w(x, h1, h2);
    s1[j] = (short)(h1 >> 16);
    s2[j] = (short)(h2 >> 16);
  }
}

// ---------------- Kernel 1: single-pass argmax, full-width staged strips ----------------
// One block per batch, 7 strips of 28 rows. Stage: ALL 256 lanes loop a linear
// index over the 28x196 strip (22 coalesced iterations; R14-16 used only
// 196/256 lanes). Col-scan then runs FROM LDS (thread j reads tile[tt][j],
// consecutive j -> conflict-free; strip/tt ascending preserves first-occurrence
// ties). Row-scan/combine unchanged.
__global__ __launch_bounds__(256) void argmax_kernel(
    const float* __restrict__ sim, int* __restrict__ idx_p, int* __restrict__ idx_i) {
  __shared__ float tile[STRIP][197];   // pad 197: staging stride coprime-ish
  __shared__ float pv[STRIP][8];
  __shared__ int   pi[STRIP][8];

  int b = blockIdx.x;
  int tid = threadIdx.x;
  const float* S = sim + (size_t)b * (TT * TT);

  float cv = -INFINITY; int ct = 0;          // column running max (thread = col j)
  int r8 = tid >> 3, p8 = tid & 7;           // row-scan role (r8 < 28)
  int cbeg = p8 * 25;
  int cend = (p8 == 7) ? 196 : (cbeg + 25);

  #pragma unroll 1
  for (int s = 0; s < 7; ++s) {
    // ---- stage strip: linear index over 28x196, all 256 lanes ----
    {
      const float* base = S + (size_t)(1 + s * STRIP) * TT + 1;
      #pragma unroll 1
      for (int i = tid; i < STRIP * SS; i += 256) {
        int tt = i / SS;                 // const-div -> magic multiply
        int c  = i - tt * SS;
        tile[tt][c] = base[(size_t)tt * TT + c];
      }
    }
    __syncthreads();

    // ---- column running max from LDS: thread j scans tile[*][j] ----
    if (tid < SS) {
      #pragma unroll
      for (int tt = 0; tt < STRIP; ++tt) {
        float x = tile[tt][tid];
        if (x > cv) { cv = x; ct = s * STRIP + tt; }   // ascending t, strict >
      }
    }

    // ---- row-argmax partials: thread (r8, p8) scans cols [cbeg, cend) ----
    if (r8 < STRIP) {                          // tid < 224
      float bv = -INFINITY; int bc = cbeg;
      for (int c = cbeg; c < cend; ++c) {
        float x = tile[r8][c];
        if (x > bv) { bv = x; bc = c; }        // ascending c, strict >
      }
      pv[r8][p8] = bv; pi[r8][p8] = bc;
    }
    __syncthreads();

    // ---- combine 8 parts (ascending part => ascending c; strict > keeps first) ----
    if (tid < STRIP) {
      float bv = pv[tid][0]; int bc = pi[tid][0];
      #pragma unroll
      for (int p = 1; p < 8; ++p) {
        float v = pv[tid][p];
        if (v > bv) { bv = v; bc = pi[tid][p]; }
      }
      idx_p[(size_t)b * SS + s * STRIP + tid] = bc;
    }
    __syncthreads();   // tile consumed; safe to overwrite next strip
  }

  if (tid < SS) idx_i[(size_t)b * SS + tid] = ct;
}

// ---------------- Kernel 2: MFMA MLP (2-split bf16, 4 passes) ----------------
// Computes exactly (a1+a2).(c1+c2) per product (only ~2^-17 split residuals
// dropped -> hidden-layer error ~1.5e-5, invisible at output bf16 ulp).
// vs R13's 3-split/6-pass: A-frags 96->64 VGPR, Bx 24->16, MFMA/nt 48->32,
// split VALU ~-40% -> attacks the occupancy/latency limit.
__global__ __launch_bounds__(256) void mlp_kernel(
    const float* __restrict__ Xp, const float* __restrict__ Xi,
    const float* __restrict__ tW1, const float* __restrict__ tb1,
    const float* __restrict__ tW2, const float* __restrict__ tb2,
    const float* __restrict__ iW1, const float* __restrict__ ib1,
    const float* __restrict__ iW2, const float* __restrict__ ib2,
    float4* __restrict__ params_t, float4* __restrict__ params_i) {
  __shared__ short  W1T2[2][64][72];   // [split][col][k] bf16, 18.4 KB
  __shared__ float4 W2s[64];
  __shared__ float  b1s[64];
  __shared__ float  b2s[4];

  int tid = threadIdx.x;
  int bid = blockIdx.x;
  int side = (bid >= MBLK) ? 1 : 0;
  const float* X  = side ? Xi  : Xp;
  const float* W1 = side ? iW1 : tW1;
  const float* B1 = side ? ib1 : tb1;
  const float* W2 = side ? iW2 : tW2;
  const float* B2 = side ? ib2 : tb2;
  float4* params  = side ? params_i : params_t;
  size_t g0 = (size_t)(side ? bid - MBLK : bid) * MROWS;

  // ---- stage W1^T split into LDS: thread (col = tid&63, kc = tid>>6) ----
  {
    int col = tid & 63, kc = tid >> 6;
    uint32_t wv[2][8];
    #pragma unroll
    for (int kk = 0; kk < 16; kk += 2) {
      float xe = W1[(size_t)(kc * 16 + kk) * 64 + col];
      float xo = W1[(size_t)(kc * 16 + kk + 1) * 64 + col];
      uint32_t e1, e2, o1, o2;
      split2w(xe, e1, e2);
      split2w(xo, o1, o2);
      wv[0][kk >> 1] = (e1 >> 16) | o1;          // lo = even k, hi = odd k
      wv[1][kk >> 1] = (e2 >> 16) | o2;
    }
    #pragma unroll
    for (int s = 0; s < 2; ++s) {
      uint32_t* dst = (uint32_t*)&W1T2[s][col][kc * 16];
      #pragma unroll
      for (int q = 0; q < 8; ++q) dst[q] = wv[s][q];
    }
  }
  if (tid < 64) {
    W2s[tid] = ((const float4*)W2)[tid];
    b1s[tid] = B1[tid];
  }
  if (tid < 4) b2s[tid] = B2[tid];
  __syncthreads();

  int w = tid >> 6, lane = tid & 63;
  int ln = lane & 15, hi = lane >> 4;
  int hi8 = hi * 8, hi4 = hi * 4;

  // A-frags (W1^T): lane holds A[m=ln][k=hi8+j] per (split, mt, ks)
  short8 Aw[2][4][2];
  #pragma unroll
  for (int s = 0; s < 2; ++s)
    #pragma unroll
    for (int mt = 0; mt < 4; ++mt)
      #pragma unroll
      for (int ks = 0; ks < 2; ++ks)
        Aw[s][mt][ks] = *(const short8*)&W1T2[s][mt * 16 + ln][ks * 32 + hi8];

  f32x4 b1v[4];
  #pragma unroll
  for (int mt = 0; mt < 4; ++mt)
    b1v[mt] = *(const f32x4*)&b1s[mt * 16 + hi4];

  size_t rowbase = g0 + (size_t)w * 64;
  // pass order: small terms first: a2c2, a2c1, a1c2, a1c1
  const int PA[4] = {1, 1, 0, 0};
  const int PB[4] = {1, 0, 1, 0};

  #pragma unroll 1
  for (int nt = 0; nt < 4; ++nt) {
    const float* xrow = X + (rowbase + nt * 16 + ln) * 64;
    f32x4 xa0 = *(const f32x4*)(xrow + hi8);
    f32x4 xa1 = *(const f32x4*)(xrow + hi8 + 4);
    f32x4 xb0 = *(const f32x4*)(xrow + 32 + hi8);
    f32x4 xb1 = *(const f32x4*)(xrow + 32 + hi8 + 4);

    short8 Bx[2][2];
    split8x2(xa0, xa1, Bx[0][0], Bx[1][0]);
    split8x2(xb0, xb1, Bx[0][1], Bx[1][1]);

    f32x4 accv[4];
    #pragma unroll
    for (int mt = 0; mt < 4; ++mt) accv[mt] = (f32x4){0.f, 0.f, 0.f, 0.f};

    #pragma unroll
    for (int p = 0; p < 4; ++p)
      #pragma unroll
      for (int mt = 0; mt < 4; ++mt)
        #pragma unroll
        for (int ks = 0; ks < 2; ++ks)
          accv[mt] = __builtin_amdgcn_mfma_f32_16x16x32_bf16(
              Aw[PA[p]][mt][ks], Bx[PB[p]][ks], accv[mt], 0, 0, 0);

    // epilogue: lane holds Y[row = rowbase+nt*16+ln][col = mt*16+hi4+v]
    float p0 = 0.f, p1 = 0.f, p2 = 0.f, p3 = 0.f;
    #pragma unroll
    for (int mt = 0; mt < 4; ++mt)
      #pragma unroll
      for (int v = 0; v < 4; ++v) {
        float y = accv[mt][v] + b1v[mt][v];
        y = fmaxf(y, 0.0f);
        float4 w2 = W2s[mt * 16 + hi4 + v];
        p0 = fmaf(y, w2.x, p0);
        p1 = fmaf(y, w2.y, p1);
        p2 = fmaf(y, w2.z, p2);
        p3 = fmaf(y, w2.w, p3);
      }
    p0 += __shfl_xor(p0, 16); p0 += __shfl_xor(p0, 32);
    p1 += __shfl_xor(p1, 16); p1 += __shfl_xor(p1, 32);
    p2 += __shfl_xor(p2, 16); p2 += __shfl_xor(p2, 32);
    p3 += __shfl_xor(p3, 16); p3 += __shfl_xor(p3, 32);

    if (lane < 16) {
      float m0 = p0 + b2s[0];
      float m1 = p1 + b2s[1];
      float s0 = __fadd_rn(softplus_(p2 + b2s[2]), 1e-07f);
      float s1 = __fadd_rn(softplus_(p3 + b2s[3]), 1e-07f);
      params[rowbase + nt * 16 + lane] = make_float4(m0, m1, s0, s1);
    }
  }
}

// ---------------- Kernel 3: gather params, sample eps, log-prob diff ----------------
__global__ __launch_bounds__(256) void combine_kernel(
    const int* __restrict__ idx_p, const int* __restrict__ idx_i,
    const float4* __restrict__ params_t, const float4* __restrict__ params_i,
    float* __restrict__ out,
    uint32_t k1a, uint32_t k1b, uint32_t k2a, uint32_t k2b) {
  int id = blockIdx.x * 256 + threadIdx.x;
  int side = (id >= MM) ? 1 : 0;             // wave-uniform (MM % 256 == 0)
  int m = id - side * MM;
  int b = m / SS;
  int t = m - b * SS;

  float4 pa, pb;
  uint32_t ka, kb;
  if (!side) {
    pa = params_t[(size_t)b * TT + 1 + t];
    pb = params_i[(size_t)b * TT + idx_p[m]];
    ka = k1a; kb = k1b;
  } else {
    pa = params_i[(size_t)b * TT + 1 + t];
    pb = params_t[(size_t)b * TT + idx_i[m]];
    ka = k2a; kb = k2b;
  }

  uint32_t e0 = 2u * (uint32_t)m;
  float eps0 = jax_normal_elem(ka, kb, e0);
  float eps1 = jax_normal_elem(ka, kb, e0 + 1u);

  float z0 = __fadd_rn(pa.x, __fmul_rn(pa.z, eps0));
  float z1 = __fadd_rn(pa.y, __fmul_rn(pa.w, eps1));

  const float HLOG2PI = 0.91893853320467274f;
  float ea0 = __fsub_rn(z0, pa.x) / pa.z;
  float ea1 = __fsub_rn(z1, pa.y) / pa.w;
  float eb0 = __fsub_rn(z0, pb.x) / pb.z;
  float eb1 = __fsub_rn(z1, pb.y) / pb.w;

  float la0 = __fsub_rn(__fsub_rn(__fmul_rn(-0.5f, __fmul_rn(ea0, ea0)), logf(pa.z)), HLOG2PI);
  float la1 = __fsub_rn(__fsub_rn(__fmul_rn(-0.5f, __fmul_rn(ea1, ea1)), logf(pa.w)), HLOG2PI);
  float lb0 = __fsub_rn(__fsub_rn(__fmul_rn(-0.5f, __fmul_rn(eb0, eb0)), logf(pb.z)), HLOG2PI);
  float lb1 = __fsub_rn(__fsub_rn(__fmul_rn(-0.5f, __fmul_rn(eb1, eb1)), logf(pb.w)), HLOG2PI);
  float lpa = __fadd_rn(la0, la1);
  float lpb = __fadd_rn(lb0, lb1);

  out[id] = sigmoid_(sigmoid_(__fsub_rn(lpa, lpb)));
}

// ---------------- Launch ----------------
extern "C" void kernel_launch(void* const* d_in, const int* in_sizes, int n_in,
                              void* d_out, int out_size, void* d_ws, size_t ws_size,
                              hipStream_t stream) {
  const float* post  = (const float*)d_in[0];
  const float* image = (const float*)d_in[1];
  const float* sim   = (const float*)d_in[2];
  const float* tW1 = (const float*)d_in[3];
  const float* tb1 = (const float*)d_in[4];
  const float* tW2 = (const float*)d_in[5];
  const float* tb2 = (const float*)d_in[6];
  const float* iW1 = (const float*)d_in[7];
  const float* ib1 = (const float*)d_in[8];
  const float* iW2 = (const float*)d_in[9];
  const float* ib2 = (const float*)d_in[10];
  float* out = (float*)d_out;

  int* idx_p = (int*)d_ws;
  int* idx_i = idx_p + MM;
  float4* params_t = (float4*)(idx_i + MM);       // GG float4s
  float4* params_i = params_t + GG;

  // jax.random.split(key(42)) under threefry_partitionable:
  // child i = full 64-bit PRF output at counter (hi=0, lo=i).
  uint32_t k1a = 0, k1b = 0; tf2x32(0u, 42u, k1a, k1b);   // child 0
  uint32_t k2a = 0, k2b = 1; tf2x32(0u, 42u, k2a, k2b);   // child 1

  argmax_kernel<<<dim3(BB), dim3(256), 0, stream>>>(sim, idx_p, idx_i);
  mlp_kernel<<<dim3(2 * MBLK), dim3(256), 0, stream>>>(
      post, image, tW1, tb1, tW2, tb2, iW1, ib1, iW2, ib2, params_t, params_i);
  combine_kernel<<<dim3((2 * MM) / 256), dim3(256), 0, stream>>>(
      idx_p, idx_i, params_t, params_i, out, k1a, k1b, k2a, k2b);
}

// Round 18
// 80.196 us; speedup vs baseline: 1.3957x; 1.3957x over previous
//
#include <hip/hip_runtime.h>
#include <stdint.h>
#include <math.h>

// Problem constants
#define BB   1024
#define TT   197
#define SS   196
#define DD   64
#define MM   200704   // BB*SS   (outputs per side)
#define GG   201728   // BB*TT   (param rows per table)
#define MROWS 256     // rows per MLP block (64 per wave)
#define MBLK  788     // GG/MROWS blocks per side
#define STRIP 28      // argmax strip rows (7 strips x 28 = 196)

using short8 = __attribute__((ext_vector_type(8))) short;   // 8 bf16 (A/B frag)
using f32x4  = __attribute__((ext_vector_type(4))) float;   // C/D frag

// ---------------- Threefry2x32 (exact JAX rolled variant) ----------------
static __host__ __device__ inline uint32_t rotl_(uint32_t x, int r) {
  return (x << r) | (x >> (32 - r));
}

static __host__ __device__ inline void tf2x32(uint32_t k0, uint32_t k1,
                                              uint32_t& x0, uint32_t& x1) {
  uint32_t ks2 = k0 ^ k1 ^ 0x1BD11BDAu;
  x0 += k0; x1 += k1;
  x0 += x1; x1 = rotl_(x1,13); x1 ^= x0;
  x0 += x1; x1 = rotl_(x1,15); x1 ^= x0;
  x0 += x1; x1 = rotl_(x1,26); x1 ^= x0;
  x0 += x1; x1 = rotl_(x1, 6); x1 ^= x0;
  x0 += k1;  x1 += ks2 + 1u;
  x0 += x1; x1 = rotl_(x1,17); x1 ^= x0;
  x0 += x1; x1 = rotl_(x1,29); x1 ^= x0;
  x0 += x1; x1 = rotl_(x1,16); x1 ^= x0;
  x0 += x1; x1 = rotl_(x1,24); x1 ^= x0;
  x0 += ks2; x1 += k0 + 2u;
  x0 += x1; x1 = rotl_(x1,13); x1 ^= x0;
  x0 += x1; x1 = rotl_(x1,15); x1 ^= x0;
  x0 += x1; x1 = rotl_(x1,26); x1 ^= x0;
  x0 += x1; x1 = rotl_(x1, 6); x1 ^= x0;
  x0 += k0;  x1 += k1 + 3u;
  x0 += x1; x1 = rotl_(x1,17); x1 ^= x0;
  x0 += x1; x1 = rotl_(x1,29); x1 ^= x0;
  x0 += x1; x1 = rotl_(x1,16); x1 ^= x0;
  x0 += x1; x1 = rotl_(x1,24); x1 ^= x0;
  x0 += k1;  x1 += ks2 + 4u;
  x0 += x1; x1 = rotl_(x1,13); x1 ^= x0;
  x0 += x1; x1 = rotl_(x1,15); x1 ^= x0;
  x0 += x1; x1 = rotl_(x1,26); x1 ^= x0;
  x0 += x1; x1 = rotl_(x1, 6); x1 ^= x0;
  x0 += ks2; x1 += k0 + 5u;
}

// XLA ErfInv (float32 Giles polynomial), exact non-contracted rounding.
static __device__ inline float erfinv_xla(float x) {
  float w = -log1pf(-__fmul_rn(x, x));
  float p;
  if (w < 5.0f) {
    w = __fsub_rn(w, 2.5f);
    p = 2.81022636e-08f;
    p = __fadd_rn(__fmul_rn(p, w), 3.43273939e-07f);
    p = __fadd_rn(__fmul_rn(p, w), -3.5233877e-06f);
    p = __fadd_rn(__fmul_rn(p, w), -4.39150654e-06f);
    p = __fadd_rn(__fmul_rn(p, w), 0.00021858087f);
    p = __fadd_rn(__fmul_rn(p, w), -0.00125372503f);
    p = __fadd_rn(__fmul_rn(p, w), -0.00417768164f);
    p = __fadd_rn(__fmul_rn(p, w), 0.246640727f);
    p = __fadd_rn(__fmul_rn(p, w), 1.50140941f);
  } else {
    w = __fsub_rn(sqrtf(w), 3.0f);
    p = -0.000200214257f;
    p = __fadd_rn(__fmul_rn(p, w), 0.000100950558f);
    p = __fadd_rn(__fmul_rn(p, w), 0.00134934322f);
    p = __fadd_rn(__fmul_rn(p, w), -0.00367342844f);
    p = __fadd_rn(__fmul_rn(p, w), 0.00573950773f);
    p = __fadd_rn(__fmul_rn(p, w), -0.0076224613f);
    p = __fadd_rn(__fmul_rn(p, w), 0.00943887047f);
    p = __fadd_rn(__fmul_rn(p, w), 1.00167406f);
    p = __fadd_rn(__fmul_rn(p, w), 2.83297682f);
  }
  return __fmul_rn(p, x);
}

// eps[e] of jax.random.normal under jax_threefry_partitionable=True:
// per-element counter PRF, counter (hi=0, lo=e), draw = x0out ^ x1out.
static __device__ inline float jax_normal_elem(uint32_t k0, uint32_t k1, uint32_t e) {
  uint32_t c0 = 0u, c1 = e;
  tf2x32(k0, k1, c0, c1);
  uint32_t bits = c0 ^ c1;
  float f = __fsub_rn(__uint_as_float((bits >> 9) | 0x3F800000u), 1.0f); // [0,1)
  const float lo = -0.99999994f;
  float u = fmaxf(lo, __fadd_rn(__fmul_rn(f, 2.0f), lo));
  return __fmul_rn(1.41421356237309515f, erfinv_xla(u));
}

static __device__ inline float softplus_(float x) {
  return __fadd_rn(fmaxf(x, 0.0f), log1pf(expf(-fabsf(x))));
}

static __device__ inline float sigmoid_(float x) {
  if (x >= 0.0f) return 1.0f / (1.0f + expf(-x));
  float e = expf(x);
  return e / (1.0f + e);
}

// 2-way truncation split of fp32 -> 2 bf16 terms (residual ~2^-17 relative)
static __device__ inline void split2w(float x, uint32_t& h1, uint32_t& h2) {
  uint32_t xb = __float_as_uint(x);
  h1 = xb & 0xFFFF0000u;
  float r1 = __fsub_rn(x, __uint_as_float(h1));   // exact
  h2 = __float_as_uint(r1) & 0xFFFF0000u;         // drops ~2^-17 residual
}

static __device__ inline void split8x2(f32x4 lo, f32x4 hi, short8& s1, short8& s2) {
  #pragma unroll
  for (int j = 0; j < 8; ++j) {
    float x = (j < 4) ? lo[j] : hi[j - 4];
    uint32_t h1, h2;
    split2w(x, h1, h2);
    s1[j] = (short)(h1 >> 16);
    s2[j] = (short)(h2 >> 16);
  }
}

// ---------------- Kernel 1: single-pass argmax, 7x28-row strips ----------------
// R16 version: thread=col staging (28 INDEPENDENT unrolled loads per strip ->
// deep memory-level parallelism; R17's linear-index staging serialized
// load->ds_write and regressed 35->89 us). Col-max fused into staging loop.
__global__ __launch_bounds__(256) void argmax_kernel(
    const float* __restrict__ sim, int* __restrict__ idx_p, int* __restrict__ idx_i) {
  __shared__ float tile[STRIP][197];   // pad 197: bank stride 5 (coprime 32)
  __shared__ float pv[STRIP][8];
  __shared__ int   pi[STRIP][8];

  int b = blockIdx.x;
  int tid = threadIdx.x;
  const float* S = sim + (size_t)b * (TT * TT);

  float cv = -INFINITY; int ct = 0;          // column running max (thread = col j)
  int r8 = tid >> 3, p8 = tid & 7;           // row-scan role (r8 < 28)
  int cbeg = p8 * 25;
  int cend = (p8 == 7) ? 196 : (cbeg + 25);

  #pragma unroll 1
  for (int s = 0; s < 7; ++s) {
    // ---- load strip rows s*28 .. s*28+27, coalesced across j ----
    if (tid < SS) {
      const float* base = S + (size_t)(1 + s * STRIP) * TT + 1 + tid;
      #pragma unroll
      for (int tt = 0; tt < STRIP; ++tt) {
        float x = base[(size_t)tt * TT];
        tile[tt][tid] = x;
        if (x > cv) { cv = x; ct = s * STRIP + tt; }   // ascending t, strict >
      }
    }
    __syncthreads();

    // ---- row-argmax partials: thread (r8, p8) scans cols [cbeg, cend) ----
    if (r8 < STRIP) {                          // tid < 224
      float bv = -INFINITY; int bc = cbeg;
      for (int c = cbeg; c < cend; ++c) {
        float x = tile[r8][c];
        if (x > bv) { bv = x; bc = c; }        // ascending c, strict >
      }
      pv[r8][p8] = bv; pi[r8][p8] = bc;
    }
    __syncthreads();

    // ---- combine 8 parts (ascending part => ascending c; strict > keeps first) ----
    if (tid < STRIP) {
      float bv = pv[tid][0]; int bc = pi[tid][0];
      #pragma unroll
      for (int p = 1; p < 8; ++p) {
        float v = pv[tid][p];
        if (v > bv) { bv = v; bc = pi[tid][p]; }
      }
      idx_p[(size_t)b * SS + s * STRIP + tid] = bc;
    }
    __syncthreads();   // tile consumed; safe to overwrite next strip
  }

  if (tid < SS) idx_i[(size_t)b * SS + tid] = ct;
}

// ---------------- Kernel 2: MFMA MLP (2-split bf16, 4 passes) ----------------
// (R17 version — measured ~10-15 us, absmax unchanged at 0.00390625)
__global__ __launch_bounds__(256) void mlp_kernel(
    const float* __restrict__ Xp, const float* __restrict__ Xi,
    const float* __restrict__ tW1, const float* __restrict__ tb1,
    const float* __restrict__ tW2, const float* __restrict__ tb2,
    const float* __restrict__ iW1, const float* __restrict__ ib1,
    const float* __restrict__ iW2, const float* __restrict__ ib2,
    float4* __restrict__ params_t, float4* __restrict__ params_i) {
  __shared__ short  W1T2[2][64][72];   // [split][col][k] bf16, 18.4 KB
  __shared__ float4 W2s[64];
  __shared__ float  b1s[64];
  __shared__ float  b2s[4];

  int tid = threadIdx.x;
  int bid = blockIdx.x;
  int side = (bid >= MBLK) ? 1 : 0;
  const float* X  = side ? Xi  : Xp;
  const float* W1 = side ? iW1 : tW1;
  const float* B1 = side ? ib1 : tb1;
  const float* W2 = side ? iW2 : tW2;
  const float* B2 = side ? ib2 : tb2;
  float4* params  = side ? params_i : params_t;
  size_t g0 = (size_t)(side ? bid - MBLK : bid) * MROWS;

  // ---- stage W1^T split into LDS: thread (col = tid&63, kc = tid>>6) ----
  {
    int col = tid & 63, kc = tid >> 6;
    uint32_t wv[2][8];
    #pragma unroll
    for (int kk = 0; kk < 16; kk += 2) {
      float xe = W1[(size_t)(kc * 16 + kk) * 64 + col];
      float xo = W1[(size_t)(kc * 16 + kk + 1) * 64 + col];
      uint32_t e1, e2, o1, o2;
      split2w(xe, e1, e2);
      split2w(xo, o1, o2);
      wv[0][kk >> 1] = (e1 >> 16) | o1;          // lo = even k, hi = odd k
      wv[1][kk >> 1] = (e2 >> 16) | o2;
    }
    #pragma unroll
    for (int s = 0; s < 2; ++s) {
      uint32_t* dst = (uint32_t*)&W1T2[s][col][kc * 16];
      #pragma unroll
      for (int q = 0; q < 8; ++q) dst[q] = wv[s][q];
    }
  }
  if (tid < 64) {
    W2s[tid] = ((const float4*)W2)[tid];
    b1s[tid] = B1[tid];
  }
  if (tid < 4) b2s[tid] = B2[tid];
  __syncthreads();

  int w = tid >> 6, lane = tid & 63;
  int ln = lane & 15, hi = lane >> 4;
  int hi8 = hi * 8, hi4 = hi * 4;

  // A-frags (W1^T): lane holds A[m=ln][k=hi8+j] per (split, mt, ks)
  short8 Aw[2][4][2];
  #pragma unroll
  for (int s = 0; s < 2; ++s)
    #pragma unroll
    for (int mt = 0; mt < 4; ++mt)
      #pragma unroll
      for (int ks = 0; ks < 2; ++ks)
        Aw[s][mt][ks] = *(const short8*)&W1T2[s][mt * 16 + ln][ks * 32 + hi8];

  f32x4 b1v[4];
  #pragma unroll
  for (int mt = 0; mt < 4; ++mt)
    b1v[mt] = *(const f32x4*)&b1s[mt * 16 + hi4];

  size_t rowbase = g0 + (size_t)w * 64;
  // pass order: small terms first: a2c2, a2c1, a1c2, a1c1
  const int PA[4] = {1, 1, 0, 0};
  const int PB[4] = {1, 0, 1, 0};

  #pragma unroll 1
  for (int nt = 0; nt < 4; ++nt) {
    const float* xrow = X + (rowbase + nt * 16 + ln) * 64;
    f32x4 xa0 = *(const f32x4*)(xrow + hi8);
    f32x4 xa1 = *(const f32x4*)(xrow + hi8 + 4);
    f32x4 xb0 = *(const f32x4*)(xrow + 32 + hi8);
    f32x4 xb1 = *(const f32x4*)(xrow + 32 + hi8 + 4);

    short8 Bx[2][2];
    split8x2(xa0, xa1, Bx[0][0], Bx[1][0]);
    split8x2(xb0, xb1, Bx[0][1], Bx[1][1]);

    f32x4 accv[4];
    #pragma unroll
    for (int mt = 0; mt < 4; ++mt) accv[mt] = (f32x4){0.f, 0.f, 0.f, 0.f};

    #pragma unroll
    for (int p = 0; p < 4; ++p)
      #pragma unroll
      for (int mt = 0; mt < 4; ++mt)
        #pragma unroll
        for (int ks = 0; ks < 2; ++ks)
          accv[mt] = __builtin_amdgcn_mfma_f32_16x16x32_bf16(
              Aw[PA[p]][mt][ks], Bx[PB[p]][ks], accv[mt], 0, 0, 0);

    // epilogue: lane holds Y[row = rowbase+nt*16+ln][col = mt*16+hi4+v]
    float p0 = 0.f, p1 = 0.f, p2 = 0.f, p3 = 0.f;
    #pragma unroll
    for (int mt = 0; mt < 4; ++mt)
      #pragma unroll
      for (int v = 0; v < 4; ++v) {
        float y = accv[mt][v] + b1v[mt][v];
        y = fmaxf(y, 0.0f);
        float4 w2 = W2s[mt * 16 + hi4 + v];
        p0 = fmaf(y, w2.x, p0);
        p1 = fmaf(y, w2.y, p1);
        p2 = fmaf(y, w2.z, p2);
        p3 = fmaf(y, w2.w, p3);
      }
    p0 += __shfl_xor(p0, 16); p0 += __shfl_xor(p0, 32);
    p1 += __shfl_xor(p1, 16); p1 += __shfl_xor(p1, 32);
    p2 += __shfl_xor(p2, 16); p2 += __shfl_xor(p2, 32);
    p3 += __shfl_xor(p3, 16); p3 += __shfl_xor(p3, 32);

    if (lane < 16) {
      float m0 = p0 + b2s[0];
      float m1 = p1 + b2s[1];
      float s0 = __fadd_rn(softplus_(p2 + b2s[2]), 1e-07f);
      float s1 = __fadd_rn(softplus_(p3 + b2s[3]), 1e-07f);
      params[rowbase + nt * 16 + lane] = make_float4(m0, m1, s0, s1);
    }
  }
}

// ---------------- Kernel 3: gather params, sample eps, log-prob diff ----------------
__global__ __launch_bounds__(256) void combine_kernel(
    const int* __restrict__ idx_p, const int* __restrict__ idx_i,
    const float4* __restrict__ params_t, const float4* __restrict__ params_i,
    float* __restrict__ out,
    uint32_t k1a, uint32_t k1b, uint32_t k2a, uint32_t k2b) {
  int id = blockIdx.x * 256 + threadIdx.x;
  int side = (id >= MM) ? 1 : 0;             // wave-uniform (MM % 256 == 0)
  int m = id - side * MM;
  int b = m / SS;
  int t = m - b * SS;

  float4 pa, pb;
  uint32_t ka, kb;
  if (!side) {
    pa = params_t[(size_t)b * TT + 1 + t];
    pb = params_i[(size_t)b * TT + idx_p[m]];
    ka = k1a; kb = k1b;
  } else {
    pa = params_i[(size_t)b * TT + 1 + t];
    pb = params_t[(size_t)b * TT + idx_i[m]];
    ka = k2a; kb = k2b;
  }

  uint32_t e0 = 2u * (uint32_t)m;
  float eps0 = jax_normal_elem(ka, kb, e0);
  float eps1 = jax_normal_elem(ka, kb, e0 + 1u);

  float z0 = __fadd_rn(pa.x, __fmul_rn(pa.z, eps0));
  float z1 = __fadd_rn(pa.y, __fmul_rn(pa.w, eps1));

  const float HLOG2PI = 0.91893853320467274f;
  float ea0 = __fsub_rn(z0, pa.x) / pa.z;
  float ea1 = __fsub_rn(z1, pa.y) / pa.w;
  float eb0 = __fsub_rn(z0, pb.x) / pb.z;
  float eb1 = __fsub_rn(z1, pb.y) / pb.w;

  float la0 = __fsub_rn(__fsub_rn(__fmul_rn(-0.5f, __fmul_rn(ea0, ea0)), logf(pa.z)), HLOG2PI);
  float la1 = __fsub_rn(__fsub_rn(__fmul_rn(-0.5f, __fmul_rn(ea1, ea1)), logf(pa.w)), HLOG2PI);
  float lb0 = __fsub_rn(__fsub_rn(__fmul_rn(-0.5f, __fmul_rn(eb0, eb0)), logf(pb.z)), HLOG2PI);
  float lb1 = __fsub_rn(__fsub_rn(__fmul_rn(-0.5f, __fmul_rn(eb1, eb1)), logf(pb.w)), HLOG2PI);
  float lpa = __fadd_rn(la0, la1);
  float lpb = __fadd_rn(lb0, lb1);

  out[id] = sigmoid_(sigmoid_(__fsub_rn(lpa, lpb)));
}

// ---------------- Launch ----------------
extern "C" void kernel_launch(void* const* d_in, const int* in_sizes, int n_in,
                              void* d_out, int out_size, void* d_ws, size_t ws_size,
                              hipStream_t stream) {
  const float* post  = (const float*)d_in[0];
  const float* image = (const float*)d_in[1];
  const float* sim   = (const float*)d_in[2];
  const float* tW1 = (const float*)d_in[3];
  const float* tb1 = (const float*)d_in[4];
  const float* tW2 = (const float*)d_in[5];
  const float* tb2 = (const float*)d_in[6];
  const float* iW1 = (const float*)d_in[7];
  const float* ib1 = (const float*)d_in[8];
  const float* iW2 = (const float*)d_in[9];
  const float* ib2 = (const float*)d_in[10];
  float* out = (float*)d_out;

  int* idx_p = (int*)d_ws;
  int* idx_i = idx_p + MM;
  float4* params_t = (float4*)(idx_i + MM);       // GG float4s
  float4* params_i = params_t + GG;

  // jax.random.split(key(42)) under threefry_partitionable:
  // child i = full 64-bit PRF output at counter (hi=0, lo=i).
  uint32_t k1a = 0, k1b = 0; tf2x32(0u, 42u, k1a, k1b);   // child 0
  uint32_t k2a = 0, k2b = 1; tf2x32(0u, 42u, k2a, k2b);   // child 1

  argmax_kernel<<<dim3(BB), dim3(256), 0, stream>>>(sim, idx_p, idx_i);
  mlp_kernel<<<dim3(2 * MBLK), dim3(256), 0, stream>>>(
      post, image, tW1, tb1, tW2, tb2, iW1, ib1, iW2, ib2, params_t, params_i);
  combine_kernel<<<dim3((2 * MM) / 256), dim3(256), 0, stream>>>(
      idx_p, idx_i, params_t, params_i, out, k1a, k1b, k2a, k2b);
}

// Round 19
// 79.612 us; speedup vs baseline: 1.4059x; 1.0073x over previous
//
#include <hip/hip_runtime.h>
#include <stdint.h>
#include <math.h>

// Problem constants
#define BB   1024
#define TT   197
#define SS   196
#define DD   64
#define MM   200704   // BB*SS   (outputs per side)
#define GG   201728   // BB*TT   (param rows per table)
#define MROWS 256     // rows per MLP block (64 per wave)
#define MBLK  788     // GG/MROWS blocks per side
#define STRIP 28      // argmax strip rows (7 strips x 28 = 196)

using short8 = __attribute__((ext_vector_type(8))) short;   // 8 bf16 (A/B frag)
using f32x4  = __attribute__((ext_vector_type(4))) float;   // C/D frag

// ---------------- Threefry2x32 (exact JAX rolled variant) ----------------
static __host__ __device__ inline uint32_t rotl_(uint32_t x, int r) {
  return (x << r) | (x >> (32 - r));
}

static __host__ __device__ inline void tf2x32(uint32_t k0, uint32_t k1,
                                              uint32_t& x0, uint32_t& x1) {
  uint32_t ks2 = k0 ^ k1 ^ 0x1BD11BDAu;
  x0 += k0; x1 += k1;
  x0 += x1; x1 = rotl_(x1,13); x1 ^= x0;
  x0 += x1; x1 = rotl_(x1,15); x1 ^= x0;
  x0 += x1; x1 = rotl_(x1,26); x1 ^= x0;
  x0 += x1; x1 = rotl_(x1, 6); x1 ^= x0;
  x0 += k1;  x1 += ks2 + 1u;
  x0 += x1; x1 = rotl_(x1,17); x1 ^= x0;
  x0 += x1; x1 = rotl_(x1,29); x1 ^= x0;
  x0 += x1; x1 = rotl_(x1,16); x1 ^= x0;
  x0 += x1; x1 = rotl_(x1,24); x1 ^= x0;
  x0 += ks2; x1 += k0 + 2u;
  x0 += x1; x1 = rotl_(x1,13); x1 ^= x0;
  x0 += x1; x1 = rotl_(x1,15); x1 ^= x0;
  x0 += x1; x1 = rotl_(x1,26); x1 ^= x0;
  x0 += x1; x1 = rotl_(x1, 6); x1 ^= x0;
  x0 += k0;  x1 += k1 + 3u;
  x0 += x1; x1 = rotl_(x1,17); x1 ^= x0;
  x0 += x1; x1 = rotl_(x1,29); x1 ^= x0;
  x0 += x1; x1 = rotl_(x1,16); x1 ^= x0;
  x0 += x1; x1 = rotl_(x1,24); x1 ^= x0;
  x0 += k1;  x1 += ks2 + 4u;
  x0 += x1; x1 = rotl_(x1,13); x1 ^= x0;
  x0 += x1; x1 = rotl_(x1,15); x1 ^= x0;
  x0 += x1; x1 = rotl_(x1,26); x1 ^= x0;
  x0 += x1; x1 = rotl_(x1, 6); x1 ^= x0;
  x0 += ks2; x1 += k0 + 5u;
}

// XLA ErfInv (float32 Giles polynomial), exact non-contracted rounding.
static __device__ inline float erfinv_xla(float x) {
  float w = -log1pf(-__fmul_rn(x, x));
  float p;
  if (w < 5.0f) {
    w = __fsub_rn(w, 2.5f);
    p = 2.81022636e-08f;
    p = __fadd_rn(__fmul_rn(p, w), 3.43273939e-07f);
    p = __fadd_rn(__fmul_rn(p, w), -3.5233877e-06f);
    p = __fadd_rn(__fmul_rn(p, w), -4.39150654e-06f);
    p = __fadd_rn(__fmul_rn(p, w), 0.00021858087f);
    p = __fadd_rn(__fmul_rn(p, w), -0.00125372503f);
    p = __fadd_rn(__fmul_rn(p, w), -0.00417768164f);
    p = __fadd_rn(__fmul_rn(p, w), 0.246640727f);
    p = __fadd_rn(__fmul_rn(p, w), 1.50140941f);
  } else {
    w = __fsub_rn(sqrtf(w), 3.0f);
    p = -0.000200214257f;
    p = __fadd_rn(__fmul_rn(p, w), 0.000100950558f);
    p = __fadd_rn(__fmul_rn(p, w), 0.00134934322f);
    p = __fadd_rn(__fmul_rn(p, w), -0.00367342844f);
    p = __fadd_rn(__fmul_rn(p, w), 0.00573950773f);
    p = __fadd_rn(__fmul_rn(p, w), -0.0076224613f);
    p = __fadd_rn(__fmul_rn(p, w), 0.00943887047f);
    p = __fadd_rn(__fmul_rn(p, w), 1.00167406f);
    p = __fadd_rn(__fmul_rn(p, w), 2.83297682f);
  }
  return __fmul_rn(p, x);
}

// eps[e] of jax.random.normal under jax_threefry_partitionable=True:
// per-element counter PRF, counter (hi=0, lo=e), draw = x0out ^ x1out.
static __device__ inline float jax_normal_elem(uint32_t k0, uint32_t k1, uint32_t e) {
  uint32_t c0 = 0u, c1 = e;
  tf2x32(k0, k1, c0, c1);
  uint32_t bits = c0 ^ c1;
  float f = __fsub_rn(__uint_as_float((bits >> 9) | 0x3F800000u), 1.0f); // [0,1)
  const float lo = -0.99999994f;
  float u = fmaxf(lo, __fadd_rn(__fmul_rn(f, 2.0f), lo));
  return __fmul_rn(1.41421356237309515f, erfinv_xla(u));
}

static __device__ inline float softplus_(float x) {
  return __fadd_rn(fmaxf(x, 0.0f), log1pf(expf(-fabsf(x))));
}

static __device__ inline float sigmoid_(float x) {
  if (x >= 0.0f) return 1.0f / (1.0f + expf(-x));
  float e = expf(x);
  return e / (1.0f + e);
}

// 2-way truncation split of fp32 -> 2 bf16 terms (residual ~2^-17 relative)
static __device__ inline void split2w(float x, uint32_t& h1, uint32_t& h2) {
  uint32_t xb = __float_as_uint(x);
  h1 = xb & 0xFFFF0000u;
  float r1 = __fsub_rn(x, __uint_as_float(h1));   // exact
  h2 = __float_as_uint(r1) & 0xFFFF0000u;         // drops ~2^-17 residual
}

static __device__ inline void split8x2(f32x4 lo, f32x4 hi, short8& s1, short8& s2) {
  #pragma unroll
  for (int j = 0; j < 8; ++j) {
    float x = (j < 4) ? lo[j] : hi[j - 4];
    uint32_t h1, h2;
    split2w(x, h1, h2);
    s1[j] = (short)(h1 >> 16);
    s2[j] = (short)(h2 >> 16);
  }
}

// ---------------- Kernel 1: single-pass argmax, register-pipelined strips ----------------
// R18 structure + T14 issue-early/write-late: strip s lives in 28 registers;
// at strip start write regs->LDS (fused col-max), then immediately ISSUE strip
// s+1's 28 independent loads (latency hides under row-scan + barriers), then
// scan. Same loads/order/tie semantics -> bit-identical indices.
__global__ __launch_bounds__(256) void argmax_kernel(
    const float* __restrict__ sim, int* __restrict__ idx_p, int* __restrict__ idx_i) {
  __shared__ float tile[STRIP][197];   // pad 197: bank stride 5 (coprime 32)
  __shared__ float pv[STRIP][8];
  __shared__ int   pi[STRIP][8];

  int b = blockIdx.x;
  int tid = threadIdx.x;
  const float* S = sim + (size_t)b * (TT * TT);

  float cv = -INFINITY; int ct = 0;          // column running max (thread = col j)
  int r8 = tid >> 3, p8 = tid & 7;           // row-scan role (r8 < 28)
  int cbeg = p8 * 25;
  int cend = (p8 == 7) ? 196 : (cbeg + 25);

  float reg[STRIP];
  // prefetch strip 0
  if (tid < SS) {
    const float* base = S + (size_t)TT + 1 + tid;   // row 1, col 1+tid
    #pragma unroll
    for (int tt = 0; tt < STRIP; ++tt) reg[tt] = base[(size_t)tt * TT];
  }

  #pragma unroll 1
  for (int s = 0; s < 7; ++s) {
    // ---- write current strip regs -> LDS, fused col running max ----
    if (tid < SS) {
      #pragma unroll
      for (int tt = 0; tt < STRIP; ++tt) {
        float x = reg[tt];
        tile[tt][tid] = x;
        if (x > cv) { cv = x; ct = s * STRIP + tt; }   // ascending t, strict >
      }
      // ---- issue next strip's loads (consumed next iteration) ----
      if (s < 6) {
        const float* nbase = S + (size_t)(1 + (s + 1) * STRIP) * TT + 1 + tid;
        #pragma unroll
        for (int tt = 0; tt < STRIP; ++tt) reg[tt] = nbase[(size_t)tt * TT];
      }
    }
    __syncthreads();

    // ---- row-argmax partials: thread (r8, p8) scans cols [cbeg, cend) ----
    if (r8 < STRIP) {                          // tid < 224
      float bv = -INFINITY; int bc = cbeg;
      for (int c = cbeg; c < cend; ++c) {
        float x = tile[r8][c];
        if (x > bv) { bv = x; bc = c; }        // ascending c, strict >
      }
      pv[r8][p8] = bv; pi[r8][p8] = bc;
    }
    __syncthreads();

    // ---- combine 8 parts (ascending part => ascending c; strict > keeps first) ----
    if (tid < STRIP) {
      float bv = pv[tid][0]; int bc = pi[tid][0];
      #pragma unroll
      for (int p = 1; p < 8; ++p) {
        float v = pv[tid][p];
        if (v > bv) { bv = v; bc = pi[tid][p]; }
      }
      idx_p[(size_t)b * SS + s * STRIP + tid] = bc;
    }
    __syncthreads();   // tile consumed; safe to overwrite next strip
  }

  if (tid < SS) idx_i[(size_t)b * SS + tid] = ct;
}

// ---------------- Kernel 2: MFMA MLP (2-split bf16, 4 passes) ----------------
// (byte-identical to R17/R18 — measured win, absmax 0.00390625)
__global__ __launch_bounds__(256) void mlp_kernel(
    const float* __restrict__ Xp, const float* __restrict__ Xi,
    const float* __restrict__ tW1, const float* __restrict__ tb1,
    const float* __restrict__ tW2, const float* __restrict__ tb2,
    const float* __restrict__ iW1, const float* __restrict__ ib1,
    const float* __restrict__ iW2, const float* __restrict__ ib2,
    float4* __restrict__ params_t, float4* __restrict__ params_i) {
  __shared__ short  W1T2[2][64][72];   // [split][col][k] bf16, 18.4 KB
  __shared__ float4 W2s[64];
  __shared__ float  b1s[64];
  __shared__ float  b2s[4];

  int tid = threadIdx.x;
  int bid = blockIdx.x;
  int side = (bid >= MBLK) ? 1 : 0;
  const float* X  = side ? Xi  : Xp;
  const float* W1 = side ? iW1 : tW1;
  const float* B1 = side ? ib1 : tb1;
  const float* W2 = side ? iW2 : tW2;
  const float* B2 = side ? ib2 : tb2;
  float4* params  = side ? params_i : params_t;
  size_t g0 = (size_t)(side ? bid - MBLK : bid) * MROWS;

  // ---- stage W1^T split into LDS: thread (col = tid&63, kc = tid>>6) ----
  {
    int col = tid & 63, kc = tid >> 6;
    uint32_t wv[2][8];
    #pragma unroll
    for (int kk = 0; kk < 16; kk += 2) {
      float xe = W1[(size_t)(kc * 16 + kk) * 64 + col];
      float xo = W1[(size_t)(kc * 16 + kk + 1) * 64 + col];
      uint32_t e1, e2, o1, o2;
      split2w(xe, e1, e2);
      split2w(xo, o1, o2);
      wv[0][kk >> 1] = (e1 >> 16) | o1;          // lo = even k, hi = odd k
      wv[1][kk >> 1] = (e2 >> 16) | o2;
    }
    #pragma unroll
    for (int s = 0; s < 2; ++s) {
      uint32_t* dst = (uint32_t*)&W1T2[s][col][kc * 16];
      #pragma unroll
      for (int q = 0; q < 8; ++q) dst[q] = wv[s][q];
    }
  }
  if (tid < 64) {
    W2s[tid] = ((const float4*)W2)[tid];
    b1s[tid] = B1[tid];
  }
  if (tid < 4) b2s[tid] = B2[tid];
  __syncthreads();

  int w = tid >> 6, lane = tid & 63;
  int ln = lane & 15, hi = lane >> 4;
  int hi8 = hi * 8, hi4 = hi * 4;

  // A-frags (W1^T): lane holds A[m=ln][k=hi8+j] per (split, mt, ks)
  short8 Aw[2][4][2];
  #pragma unroll
  for (int s = 0; s < 2; ++s)
    #pragma unroll
    for (int mt = 0; mt < 4; ++mt)
      #pragma unroll
      for (int ks = 0; ks < 2; ++ks)
        Aw[s][mt][ks] = *(const short8*)&W1T2[s][mt * 16 + ln][ks * 32 + hi8];

  f32x4 b1v[4];
  #pragma unroll
  for (int mt = 0; mt < 4; ++mt)
    b1v[mt] = *(const f32x4*)&b1s[mt * 16 + hi4];

  size_t rowbase = g0 + (size_t)w * 64;
  // pass order: small terms first: a2c2, a2c1, a1c2, a1c1
  const int PA[4] = {1, 1, 0, 0};
  const int PB[4] = {1, 0, 1, 0};

  #pragma unroll 1
  for (int nt = 0; nt < 4; ++nt) {
    const float* xrow = X + (rowbase + nt * 16 + ln) * 64;
    f32x4 xa0 = *(const f32x4*)(xrow + hi8);
    f32x4 xa1 = *(const f32x4*)(xrow + hi8 + 4);
    f32x4 xb0 = *(const f32x4*)(xrow + 32 + hi8);
    f32x4 xb1 = *(const f32x4*)(xrow + 32 + hi8 + 4);

    short8 Bx[2][2];
    split8x2(xa0, xa1, Bx[0][0], Bx[1][0]);
    split8x2(xb0, xb1, Bx[0][1], Bx[1][1]);

    f32x4 accv[4];
    #pragma unroll
    for (int mt = 0; mt < 4; ++mt) accv[mt] = (f32x4){0.f, 0.f, 0.f, 0.f};

    #pragma unroll
    for (int p = 0; p < 4; ++p)
      #pragma unroll
      for (int mt = 0; mt < 4; ++mt)
        #pragma unroll
        for (int ks = 0; ks < 2; ++ks)
          accv[mt] = __builtin_amdgcn_mfma_f32_16x16x32_bf16(
              Aw[PA[p]][mt][ks], Bx[PB[p]][ks], accv[mt], 0, 0, 0);

    // epilogue: lane holds Y[row = rowbase+nt*16+ln][col = mt*16+hi4+v]
    float p0 = 0.f, p1 = 0.f, p2 = 0.f, p3 = 0.f;
    #pragma unroll
    for (int mt = 0; mt < 4; ++mt)
      #pragma unroll
      for (int v = 0; v < 4; ++v) {
        float y = accv[mt][v] + b1v[mt][v];
        y = fmaxf(y, 0.0f);
        float4 w2 = W2s[mt * 16 + hi4 + v];
        p0 = fmaf(y, w2.x, p0);
        p1 = fmaf(y, w2.y, p1);
        p2 = fmaf(y, w2.z, p2);
        p3 = fmaf(y, w2.w, p3);
      }
    p0 += __shfl_xor(p0, 16); p0 += __shfl_xor(p0, 32);
    p1 += __shfl_xor(p1, 16); p1 += __shfl_xor(p1, 32);
    p2 += __shfl_xor(p2, 16); p2 += __shfl_xor(p2, 32);
    p3 += __shfl_xor(p3, 16); p3 += __shfl_xor(p3, 32);

    if (lane < 16) {
      float m0 = p0 + b2s[0];
      float m1 = p1 + b2s[1];
      float s0 = __fadd_rn(softplus_(p2 + b2s[2]), 1e-07f);
      float s1 = __fadd_rn(softplus_(p3 + b2s[3]), 1e-07f);
      params[rowbase + nt * 16 + lane] = make_float4(m0, m1, s0, s1);
    }
  }
}

// ---------------- Kernel 3: gather params, sample eps, log-prob diff ----------------
__global__ __launch_bounds__(256) void combine_kernel(
    const int* __restrict__ idx_p, const int* __restrict__ idx_i,
    const float4* __restrict__ params_t, const float4* __restrict__ params_i,
    float* __restrict__ out,
    uint32_t k1a, uint32_t k1b, uint32_t k2a, uint32_t k2b) {
  int id = blockIdx.x * 256 + threadIdx.x;
  int side = (id >= MM) ? 1 : 0;             // wave-uniform (MM % 256 == 0)
  int m = id - side * MM;
  int b = m / SS;
  int t = m - b * SS;

  float4 pa, pb;
  uint32_t ka, kb;
  if (!side) {
    pa = params_t[(size_t)b * TT + 1 + t];
    pb = params_i[(size_t)b * TT + idx_p[m]];
    ka = k1a; kb = k1b;
  } else {
    pa = params_i[(size_t)b * TT + 1 + t];
    pb = params_t[(size_t)b * TT + idx_i[m]];
    ka = k2a; kb = k2b;
  }

  uint32_t e0 = 2u * (uint32_t)m;
  float eps0 = jax_normal_elem(ka, kb, e0);
  float eps1 = jax_normal_elem(ka, kb, e0 + 1u);

  float z0 = __fadd_rn(pa.x, __fmul_rn(pa.z, eps0));
  float z1 = __fadd_rn(pa.y, __fmul_rn(pa.w, eps1));

  const float HLOG2PI = 0.91893853320467274f;
  float ea0 = __fsub_rn(z0, pa.x) / pa.z;
  float ea1 = __fsub_rn(z1, pa.y) / pa.w;
  float eb0 = __fsub_rn(z0, pb.x) / pb.z;
  float eb1 = __fsub_rn(z1, pb.y) / pb.w;

  float la0 = __fsub_rn(__fsub_rn(__fmul_rn(-0.5f, __fmul_rn(ea0, ea0)), logf(pa.z)), HLOG2PI);
  float la1 = __fsub_rn(__fsub_rn(__fmul_rn(-0.5f, __fmul_rn(ea1, ea1)), logf(pa.w)), HLOG2PI);
  float lb0 = __fsub_rn(__fsub_rn(__fmul_rn(-0.5f, __fmul_rn(eb0, eb0)), logf(pb.z)), HLOG2PI);
  float lb1 = __fsub_rn(__fsub_rn(__fmul_rn(-0.5f, __fmul_rn(eb1, eb1)), logf(pb.w)), HLOG2PI);
  float lpa = __fadd_rn(la0, la1);
  float lpb = __fadd_rn(lb0, lb1);

  out[id] = sigmoid_(sigmoid_(__fsub_rn(lpa, lpb)));
}

// ---------------- Launch ----------------
extern "C" void kernel_launch(void* const* d_in, const int* in_sizes, int n_in,
                              void* d_out, int out_size, void* d_ws, size_t ws_size,
                              hipStream_t stream) {
  const float* post  = (const float*)d_in[0];
  const float* image = (const float*)d_in[1];
  const float* sim   = (const float*)d_in[2];
  const float* tW1 = (const float*)d_in[3];
  const float* tb1 = (const float*)d_in[4];
  const float* tW2 = (const float*)d_in[5];
  const float* tb2 = (const float*)d_in[6];
  const float* iW1 = (const float*)d_in[7];
  const float* ib1 = (const float*)d_in[8];
  const float* iW2 = (const float*)d_in[9];
  const float* ib2 = (const float*)d_in[10];
  float* out = (float*)d_out;

  int* idx_p = (int*)d_ws;
  int* idx_i = idx_p + MM;
  float4* params_t = (float4*)(idx_i + MM);       // GG float4s
  float4* params_i = params_t + GG;

  // jax.random.split(key(42)) under threefry_partitionable:
  // child i = full 64-bit PRF output at counter (hi=0, lo=i).
  uint32_t k1a = 0, k1b = 0; tf2x32(0u, 42u, k1a, k1b);   // child 0
  uint32_t k2a = 0, k2b = 1; tf2x32(0u, 42u, k2a, k2b);   // child 1

  argmax_kernel<<<dim3(BB), dim3(256), 0, stream>>>(sim, idx_p, idx_i);
  mlp_kernel<<<dim3(2 * MBLK), dim3(256), 0, stream>>>(
      post, image, tW1, tb1, tW2, tb2, iW1, ib1, iW2, ib2, params_t, params_i);
  combine_kernel<<<dim3((2 * MM) / 256), dim3(256), 0, stream>>>(
      idx_p, idx_i, params_t, params_i, out, k1a, k1b, k2a, k2b);
}